// Round 1
// baseline (531.996 us; speedup 1.0000x reference)
//
#include <hip/hip_runtime.h>

constexpr int FD = 128;

// ---- monotone float<->uint encoding for atomic max over floats ----
__device__ __forceinline__ unsigned fenc(float f) {
    unsigned u = __float_as_uint(f);
    return (u & 0x80000000u) ? ~u : (u | 0x80000000u);
}
__device__ __forceinline__ float fdec(unsigned e) {
    return (e & 0x80000000u) ? __uint_as_float(e & 0x7fffffffu)
                             : __uint_as_float(~e);
}

// ---- zero degree histogram, init max slot to encoded(-inf) ----
__global__ void init_kernel(int* __restrict__ deg, unsigned* __restrict__ maxslot, int n) {
    int i = blockIdx.x * blockDim.x + threadIdx.x;
    if (i < n) deg[i] = 0;
    if (i == 0) *maxslot = 0x007FFFFFu;  // fenc(-inf)
}

// ---- Wh = h @ W^T  (fp32 vector ALU; 16 rows/block, thread = one out column) ----
__global__ __launch_bounds__(256) void gemm_kernel(const float* __restrict__ h,
                                                   const float* __restrict__ W,
                                                   float* __restrict__ Wh, int n) {
    __shared__ float hs[16 * FD];  // 8 KB
    int tid = threadIdx.x;
    int rbase = blockIdx.x * 16;

    // stage 16 rows of h into LDS (coalesced float4)
    {
        const float4* h4 = (const float4*)(h + (size_t)rbase * FD);
        float4* hs4 = (float4*)hs;
        int r0 = rbase + (tid >> 5);          // tid*4/128
        int r1 = rbase + ((tid + 256) >> 5);
        hs4[tid]       = (r0 < n) ? h4[tid]       : make_float4(0.f, 0.f, 0.f, 0.f);
        hs4[tid + 256] = (r1 < n) ? h4[tid + 256] : make_float4(0.f, 0.f, 0.f, 0.f);
    }
    __syncthreads();

    int j = tid & 127;   // output column
    int g = tid >> 7;    // row-group 0/1 (8 rows each)
    float acc[8] = {0.f, 0.f, 0.f, 0.f, 0.f, 0.f, 0.f, 0.f};
    const float4* W4 = (const float4*)(W + (size_t)j * FD);  // row j of W

#pragma unroll 4
    for (int k4 = 0; k4 < 32; ++k4) {
        float4 w = W4[k4];
#pragma unroll
        for (int rr = 0; rr < 8; ++rr) {
            float4 hv = ((const float4*)(hs + (g * 8 + rr) * FD))[k4];  // LDS broadcast
            acc[rr] = fmaf(w.x, hv.x, acc[rr]);
            acc[rr] = fmaf(w.y, hv.y, acc[rr]);
            acc[rr] = fmaf(w.z, hv.z, acc[rr]);
            acc[rr] = fmaf(w.w, hv.w, acc[rr]);
        }
    }
#pragma unroll
    for (int rr = 0; rr < 8; ++rr) {
        int r = rbase + g * 8 + rr;
        if (r < n) Wh[(size_t)r * FD + j] = acc[rr];  // coalesced over j
    }
}

// ---- s1[r] = Wh[r]·a1 ; s2[r] = Wh[r]·a2  (one wave per row) ----
__global__ __launch_bounds__(256) void s12_kernel(const float* __restrict__ Wh,
                                                  const float* __restrict__ a,
                                                  float* __restrict__ s1,
                                                  float* __restrict__ s2, int n) {
    int wid = threadIdx.x >> 6, lane = threadIdx.x & 63;
    int r = blockIdx.x * 4 + wid;
    if (r >= n) return;
    float2 wh = *(const float2*)(Wh + (size_t)r * FD + 2 * lane);
    float2 a1 = *(const float2*)(a + 2 * lane);
    float2 a2 = *(const float2*)(a + FD + 2 * lane);
    float p1 = fmaf(wh.x, a1.x, wh.y * a1.y);
    float p2 = fmaf(wh.x, a2.x, wh.y * a2.y);
#pragma unroll
    for (int d = 1; d < 64; d <<= 1) {
        p1 += __shfl_xor(p1, d, 64);
        p2 += __shfl_xor(p2, d, 64);
    }
    if (lane == 0) { s1[r] = p1; s2[r] = p2; }
}

// ---- per-edge degree histogram ----
__global__ __launch_bounds__(256) void deg_kernel(const int* __restrict__ ei,
                                                  int* __restrict__ deg, int e_cnt) {
    int e = blockIdx.x * blockDim.x + threadIdx.x;
    if (e < e_cnt) atomicAdd(&deg[ei[e]], 1);
}

// ---- single-block exclusive scan of degrees -> rowptr, cursor ----
__global__ __launch_bounds__(1024) void scan_kernel(const int* __restrict__ deg,
                                                    int* __restrict__ rowptr,
                                                    int* __restrict__ cursor, int n) {
    __shared__ int ssum[1024];
    int t = threadIdx.x;
    int chunk = (n + 1023) >> 10;
    int b = t * chunk, e = min(b + chunk, n);
    int local = 0;
    for (int i = b; i < e; ++i) local += deg[i];
    ssum[t] = local;
    __syncthreads();
    for (int off = 1; off < 1024; off <<= 1) {
        int v = (t >= off) ? ssum[t - off] : 0;
        __syncthreads();
        ssum[t] += v;
        __syncthreads();
    }
    int run = (t > 0) ? ssum[t - 1] : 0;  // exclusive prefix
    for (int i = b; i < e; ++i) {
        rowptr[i] = run;
        cursor[i] = run;
        run += deg[i];
    }
    if (t == 1023) rowptr[n] = ssum[1023];  // == E
}

// ---- fill CSR (col + leaky-relu score), reduce global max score ----
__global__ __launch_bounds__(256) void fill_kernel(const int* __restrict__ ei,
                                                   const float* __restrict__ s1,
                                                   const float* __restrict__ s2,
                                                   int* __restrict__ cursor,
                                                   int* __restrict__ csr_col,
                                                   float* __restrict__ csr_sc,
                                                   unsigned* __restrict__ maxslot,
                                                   int e_cnt) {
    int e = blockIdx.x * blockDim.x + threadIdx.x;
    float le = -3.0e38f;
    if (e < e_cnt) {
        int r = ei[e];
        int c = ei[e_cnt + e];
        float sc = s1[r] + s2[c];
        le = (sc >= 0.f) ? sc : 0.2f * sc;  // leaky_relu, slope 0.2
        int pos = atomicAdd(&cursor[r], 1);
        csr_col[pos] = c;
        csr_sc[pos] = le;
    }
    float m = le;
#pragma unroll
    for (int d = 1; d < 64; d <<= 1) m = fmaxf(m, __shfl_xor(m, d, 64));
    if ((threadIdx.x & 63) == 0) atomicMax(maxslot, fenc(m));
}

// ---- per-node softmax + weighted gather-aggregate + elu (one wave/node) ----
__global__ __launch_bounds__(256) void agg_kernel(const int* __restrict__ rowptr,
                                                  const int* __restrict__ csr_col,
                                                  const float* __restrict__ csr_sc,
                                                  const float* __restrict__ Wh,
                                                  const unsigned* __restrict__ maxslot,
                                                  float* __restrict__ out, int n) {
    int wid = threadIdx.x >> 6, lane = threadIdx.x & 63;
    int node = blockIdx.x * 4 + wid;
    if (node >= n) return;
    float M = fdec(*maxslot);
    int start = rowptr[node], end = rowptr[node + 1];

    // pass 1: sum of exp over this node's edges (lane-parallel)
    float psum = 0.f;
    for (int j = start + lane; j < end; j += 64) psum += expf(csr_sc[j] - M);
#pragma unroll
    for (int d = 1; d < 64; d <<= 1) psum += __shfl_xor(psum, d, 64);
    float inv = 1.0f / (psum + 1e-10f);

    // pass 2: acc += alpha_j * Wh[col_j][2*lane .. 2*lane+1]
    float ax = 0.f, ay = 0.f;
    for (int j = start; j < end; ++j) {
        float w = expf(csr_sc[j] - M) * inv;   // broadcast-read, redundant exp (cheap)
        int c = csr_col[j];
        float2 wh = *(const float2*)(Wh + (size_t)c * FD + 2 * lane);  // coalesced 512B/row
        ax = fmaf(w, wh.x, ax);
        ay = fmaf(w, wh.y, ay);
    }
    float ox = (ax > 0.f) ? ax : expm1f(ax);   // elu, alpha=1
    float oy = (ay > 0.f) ? ay : expm1f(ay);
    *(float2*)(out + (size_t)node * FD + 2 * lane) = make_float2(ox, oy);
}

extern "C" void kernel_launch(void* const* d_in, const int* in_sizes, int n_in,
                              void* d_out, int out_size, void* d_ws, size_t ws_size,
                              hipStream_t stream) {
    const float* h = (const float*)d_in[0];
    const int* ei  = (const int*)d_in[1];
    const float* W = (const float*)d_in[2];
    const float* a = (const float*)d_in[3];
    float* out = (float*)d_out;
    int n = in_sizes[0] / FD;   // 50000
    int e = in_sizes[1] / 2;    // 800000

    // workspace carve-up (256B aligned); total ~33 MB
    char* ws = (char*)d_ws;
    size_t off = 0;
    auto alloc = [&](size_t bytes) -> void* {
        void* p = ws + off;
        off += bytes;
        off = (off + 255) & ~(size_t)255;
        return p;
    };
    float*    Wh      = (float*)alloc((size_t)n * FD * sizeof(float));
    float*    s1      = (float*)alloc((size_t)n * sizeof(float));
    float*    s2      = (float*)alloc((size_t)n * sizeof(float));
    int*      deg     = (int*)alloc((size_t)n * sizeof(int));
    int*      rowptr  = (int*)alloc((size_t)(n + 1) * sizeof(int));
    int*      cursor  = (int*)alloc((size_t)n * sizeof(int));
    int*      csr_col = (int*)alloc((size_t)e * sizeof(int));
    float*    csr_sc  = (float*)alloc((size_t)e * sizeof(float));
    unsigned* maxslot = (unsigned*)alloc(sizeof(unsigned));

    init_kernel<<<(n + 255) / 256, 256, 0, stream>>>(deg, maxslot, n);
    gemm_kernel<<<(n + 15) / 16, 256, 0, stream>>>(h, W, Wh, n);
    deg_kernel<<<(e + 255) / 256, 256, 0, stream>>>(ei, deg, e);
    s12_kernel<<<(n + 3) / 4, 256, 0, stream>>>(Wh, a, s1, s2, n);
    scan_kernel<<<1, 1024, 0, stream>>>(deg, rowptr, cursor, n);
    fill_kernel<<<(e + 255) / 256, 256, 0, stream>>>(ei, s1, s2, cursor, csr_col, csr_sc, maxslot, e);
    agg_kernel<<<(n + 3) / 4, 256, 0, stream>>>(rowptr, csr_col, csr_sc, Wh, maxslot, out, n);
}